// Round 3
// baseline (176.237 us; speedup 1.0000x reference)
//
#include <hip/hip_runtime.h>
#include <stdint.h>

#define B_ROWS 4096
#define C_OUT  2048
#define C_IN   2048
#define EPS    1e-5f

typedef __attribute__((ext_vector_type(8))) short bf16x8;  // 8 bf16 = 4 VGPRs
typedef __attribute__((ext_vector_type(4))) float f32x4;

// RNE f32 -> bf16
__device__ __forceinline__ unsigned short f2bf(float f) {
    uint32_t u = __float_as_uint(f);
    uint32_t r = (u + 0x7fffu + ((u >> 16) & 1u)) >> 16;
    return (unsigned short)r;
}

// One launch converts both x and w (f32 -> bf16, float4-granular)
__global__ void cvt_f32_bf16_kernel(const float* __restrict__ x,
                                    const float* __restrict__ w,
                                    unsigned short* __restrict__ xb,
                                    unsigned short* __restrict__ wb,
                                    int nx4, int nw4) {
    int i = blockIdx.x * blockDim.x + threadIdx.x;
    const float* src;
    unsigned short* dst;
    if (i < nx4) {
        src = x; dst = xb;
    } else {
        i -= nx4;
        if (i >= nw4) return;
        src = w; dst = wb;
    }
    float4 v = ((const float4*)src)[i];
    ushort4 o;
    o.x = f2bf(v.x); o.y = f2bf(v.y); o.z = f2bf(v.z); o.w = f2bf(v.w);
    ((ushort4*)dst)[i] = o;
}

// R9: the session's kernels (R6 41.7, R7 46.2, R8 43.3 us) are all
// LDS-PIPE-BANDWIDTH-BOUND: ~180-190 KB LDS traffic per K-tile per CU
// (frag reads 131 KB + staging writes 48 KB) ~ 2100 cyc @ 85 B/cyc vs the
// 1242-cyc MFMA floor. Wave-geometry math: with 8 waves/CU and fixed 32K
// output cells/CU, 64x64 wave tiles already MINIMIZE frag-read bytes -> the
// only way down is removing an operand from LDS.
//   => A-operand goes GLOBAL->REG directly (lane reads A[row][k+quad*8], 16 B
//      contiguous = exact MFMA A-fragment, no shuffle). LDS becomes B-only:
//      80 KB/K-tile (~950 cyc) < MFMA 1242 -> matrix-pipe-bound.
//   => A-loads issued one K-tile (~1500 cyc) ahead, register-double-buffered;
//      compiler's exact auto-waitcnt covers A-reg/B-ds deps. Only manual wait:
//      stage-guard vmcnt(9) (= ops issued after stage(kt+1)h1: 4A+1stage+4A;
//      8 at kt=30), with sched_barrier(0) fences pinning VMEM issue order.
//   => A L2 locality: bijective XCD swizzle chunks blocks by A-panel: XCD x
//      (bid%8, rr dispatch) gets br in {2x,2x+1} -> 2 MB A resident per XCD-L2;
//      B (8 MB total) streams via L3.
//   LDS: 3 x 16 KB B tiles (48 KB). 2 barriers/K-tile. Epilogue unchanged
//   (wave's 64 cols = one GN group, per-wave shfl stats).
__global__ __launch_bounds__(512, 2)
void gemm_gn_kernel(const unsigned short* __restrict__ A,  // [4096][2048] bf16
                    const unsigned short* __restrict__ W,  // [2048][2048] bf16
                    const float* __restrict__ bias,
                    const float* __restrict__ gnw,
                    const float* __restrict__ gnb,
                    float* __restrict__ out) {
    __shared__ __align__(16) unsigned short smem[3 * 8192];  // 48 KB, B only

    // XCD swizzle: rr dispatch puts bid%8 on XCD (bid%8); give each XCD a
    // contiguous br-pair so its A working set is 2 panels = 2 MB (L2-fit).
    const int bid = blockIdx.x;            // 0..255
    const int xcd = bid & 7;
    const int t2  = bid >> 3;              // 0..31
    const int br  = 2 * xcd + (t2 >> 4);   // 0..15 row block (256 rows)
    const int bc  = t2 & 15;               // 0..15 col block (128 cols)

    const int tid  = threadIdx.x;     // 0..511
    const int lane = tid & 63;
    const int wave = tid >> 6;        // 0..7
    const int wr   = wave >> 1;       // 0..3 row quarter (64 rows)
    const int wc   = wave & 1;        // 0..1 col half (64 cols = 1 group)
    const int c16  = lane & 15;
    const int quad = lane >> 4;

    f32x4 acc[4][4];
#pragma unroll
    for (int i = 0; i < 4; i++)
#pragma unroll
        for (int j = 0; j < 4; j++) acc[i][j] = (f32x4){0.f, 0.f, 0.f, 0.f};

    // ---- B staging addresses (granule-XOR swizzle, pre-swizzled global src,
    //      linear LDS dest; verified 0-conflict in R4/R6/R8) ----
    const int r0 = tid >> 3;                        // 0..63
    const int qo = ((tid & 7) ^ (r0 & 7)) * 8;      // element offset in row
    const unsigned short* gB = W + (size_t)(bc * 128 + r0) * C_IN + qo;
    const int t8 = tid * 8;

    // half 0: B rows 0..63, half 1: rows 64..127 (1 global_load_lds each)
#define STAGE_B(dst, k0, half)                                                                      \
    __builtin_amdgcn_global_load_lds(                                                               \
        (const __attribute__((address_space(1))) void*)(gB + (size_t)((half) * 64) * C_IN + (k0)),  \
        (__attribute__((address_space(3))) void*)((dst) + (half) * 4096 + t8), 16, 0, 0)

    unsigned short* bf0 = smem;
    unsigned short* bf1 = smem + 8192;
    unsigned short* bf2 = smem + 16384;

    // B frag addressing: logical granule q at phys q ^ (c16&7)
    const int qs0 = (quad ^ (c16 & 7)) * 8;        // kk=0
    const int qs1 = ((4 + quad) ^ (c16 & 7)) * 8;  // kk=1
    int offB[4];
#pragma unroll
    for (int j = 0; j < 4; j++) offB[j] = (wc * 64 + j * 16 + c16) * 64;

    // A direct-load pointers: lane's frag i = A[br*256+wr*64+i*16+c16][k+quad*8]
    const unsigned short* pA[4];
#pragma unroll
    for (int i = 0; i < 4; i++)
        pA[i] = A + (size_t)(br * 256 + wr * 64 + i * 16 + c16) * C_IN + quad * 8;

    // ---- prologue: stage B tiles 0,1; load A tile 0 (both kk) ----
    STAGE_B(bf0, 0, 0);  STAGE_B(bf0, 0, 1);
    STAGE_B(bf1, 64, 0); STAGE_B(bf1, 64, 1);
    bf16x8 ac0[4], ac1[4], an0[4], an1[4], b0[4], b1[4];
#pragma unroll
    for (int i = 0; i < 4; i++) ac0[i] = *(const bf16x8*)(pA[i]);
#pragma unroll
    for (int i = 0; i < 4; i++) ac1[i] = *(const bf16x8*)(pA[i] + 32);
    asm volatile("s_waitcnt vmcnt(8)" ::: "memory");  // B tiles 0,1 landed; A in flight
    __builtin_amdgcn_s_barrier();

    const unsigned short* pr = bf0;   // read:  B tile kt
    const unsigned short* pn = bf1;   // ready: B tile kt+1
    unsigned short*       ps = bf2;   // stage: B tile kt+2

    // pre-read B(0, kk0) frags
#pragma unroll
    for (int j = 0; j < 4; j++) b0[j] = *(const bf16x8*)(pr + offB[j] + qs0);

#pragma unroll 2
    for (int kt = 0; kt < 32; ++kt) {
        const int k2 = (kt + 2) * 64;

        // ---------- phase 0: MFMA(A kk0, B kk0); prefetch ----------
#pragma unroll
        for (int j = 0; j < 4; j++) b1[j] = *(const bf16x8*)(pr + offB[j] + qs1);
        __builtin_amdgcn_sched_barrier(0);
        if (kt < 30) STAGE_B(ps, k2, 0);
        __builtin_amdgcn_sched_barrier(0);
        if (kt < 31) {
#pragma unroll
            for (int i = 0; i < 4; i++) an0[i] = *(const bf16x8*)(pA[i] + (kt + 1) * 64);
        }
        __builtin_amdgcn_sched_barrier(0);
        __builtin_amdgcn_s_setprio(1);
#pragma unroll
        for (int i = 0; i < 4; i++)
#pragma unroll
            for (int j = 0; j < 4; j++)
                acc[i][j] = __builtin_amdgcn_mfma_f32_16x16x32_bf16(ac0[i], b0[j], acc[i][j], 0, 0, 0);
        __builtin_amdgcn_s_setprio(0);

        // ---------- phase 1: MFMA(A kk1, B kk1); next-tile B reads ----------
        if (kt < 31) {
            // stage-guard: this wave's stage(kt+1) ops have 9 (8 at kt==30)
            // newer VMEM ops -> vmcnt(N) proves they completed. barrier makes
            // it block-wide, then pn is safe to ds_read.
            if (kt < 30) asm volatile("s_waitcnt vmcnt(9)" ::: "memory");
            else         asm volatile("s_waitcnt vmcnt(8)" ::: "memory");
            __builtin_amdgcn_s_barrier();
#pragma unroll
            for (int j = 0; j < 4; j++) b0[j] = *(const bf16x8*)(pn + offB[j] + qs0);
        }
        __builtin_amdgcn_sched_barrier(0);
        if (kt < 30) STAGE_B(ps, k2, 1);
        __builtin_amdgcn_sched_barrier(0);
        if (kt < 31) {
#pragma unroll
            for (int i = 0; i < 4; i++) an1[i] = *(const bf16x8*)(pA[i] + (kt + 1) * 64 + 32);
        }
        __builtin_amdgcn_sched_barrier(0);
        __builtin_amdgcn_s_setprio(1);
#pragma unroll
        for (int i = 0; i < 4; i++)
#pragma unroll
            for (int j = 0; j < 4; j++)
                acc[i][j] = __builtin_amdgcn_mfma_f32_16x16x32_bf16(ac1[i], b1[j], acc[i][j], 0, 0, 0);
        __builtin_amdgcn_s_setprio(0);
        // end-of-tile: all waves' reads of pr done (auto-lgkm before MFMAs) ->
        // next tile may stage into old pr.
        if (kt < 31) __builtin_amdgcn_s_barrier();

        // rotate buffers + A register double-buffer
        const unsigned short* tmp = pr;
        pr = pn;
        pn = ps;
        ps = (unsigned short*)tmp;
#pragma unroll
        for (int i = 0; i < 4; i++) { ac0[i] = an0[i]; ac1[i] = an1[i]; }
    }

    // ---- epilogue: bias + GroupNorm + hardtanh (all 8 waves, no LDS) ----
    // acc[i][j][r]: row = br*256 + wr*64 + i*16 + quad*4 + r,
    //               col = bc*128 + wc*64 + j*16 + c16. Wave's 64 cols = 1 group.
    const int colbase = bc * 128 + wc * 64;
    const int rowbase = br * 256 + wr * 64;
    float bv[4], gw[4], gb[4];
#pragma unroll
    for (int j = 0; j < 4; j++) {
        int col = colbase + j * 16 + c16;
        bv[j] = bias[col];
        gw[j] = gnw[col];
        gb[j] = gnb[col];
    }
#pragma unroll
    for (int i = 0; i < 4; i++) {
#pragma unroll
        for (int r = 0; r < 4; r++) {
            float s = 0.f, ss = 0.f;
#pragma unroll
            for (int j = 0; j < 4; j++) {
                float v = acc[i][j][r] + bv[j];
                acc[i][j][r] = v;
                s += v;
                ss += v * v;
            }
#pragma unroll
            for (int m = 1; m < 16; m <<= 1) {
                s  += __shfl_xor(s, m, 64);
                ss += __shfl_xor(ss, m, 64);
            }
            float mean = s * (1.f / 64.f);
            float var  = ss * (1.f / 64.f) - mean * mean;
            float rstd = rsqrtf(var + EPS);
            int row = rowbase + i * 16 + quad * 4 + r;
            float* orow = out + (size_t)row * C_OUT;
#pragma unroll
            for (int j = 0; j < 4; j++) {
                float v = (acc[i][j][r] - mean) * rstd * gw[j] + gb[j];
                v = fminf(1.f, fmaxf(-1.f, v));
                orow[colbase + j * 16 + c16] = v;
            }
        }
    }
}

extern "C" void kernel_launch(void* const* d_in, const int* in_sizes, int n_in,
                              void* d_out, int out_size, void* d_ws, size_t ws_size,
                              hipStream_t stream) {
    const float* x    = (const float*)d_in[0];   // [4096, 2048]
    const float* w    = (const float*)d_in[1];   // [2048, 2048]
    const float* bias = (const float*)d_in[2];   // [2048]
    const float* gnw  = (const float*)d_in[3];   // [2048]
    const float* gnb  = (const float*)d_in[4];   // [2048]
    float* out = (float*)d_out;

    unsigned short* xb = (unsigned short*)d_ws;                        // 16 MB
    unsigned short* wb = xb + (size_t)B_ROWS * C_IN;                   //  8 MB

    const int nx4 = B_ROWS * C_IN / 4;   // 2097152
    const int nw4 = C_OUT * C_IN / 4;    // 1048576
    cvt_f32_bf16_kernel<<<(nx4 + nw4 + 255) / 256, 256, 0, stream>>>(x, w, xb, wb, nx4, nw4);

    gemm_gn_kernel<<<256, 512, 0, stream>>>(xb, wb, bias, gnw, gnb, out);
}

// Round 4
// 139.201 us; speedup vs baseline: 1.2661x; 1.2661x over previous
//
#include <hip/hip_runtime.h>
#include <stdint.h>

#define B_ROWS 4096
#define C_OUT  2048
#define C_IN   2048
#define EPS    1e-5f

typedef __attribute__((ext_vector_type(8))) short bf16x8;  // 8 bf16 = 4 VGPRs
typedef __attribute__((ext_vector_type(4))) float f32x4;

// RNE f32 -> bf16
__device__ __forceinline__ unsigned short f2bf(float f) {
    uint32_t u = __float_as_uint(f);
    uint32_t r = (u + 0x7fffu + ((u >> 16) & 1u)) >> 16;
    return (unsigned short)r;
}

// One launch converts both x and w (f32 -> bf16, float4-granular)
__global__ void cvt_f32_bf16_kernel(const float* __restrict__ x,
                                    const float* __restrict__ w,
                                    unsigned short* __restrict__ xb,
                                    unsigned short* __restrict__ wb,
                                    int nx4, int nw4) {
    int i = blockIdx.x * blockDim.x + threadIdx.x;
    const float* src;
    unsigned short* dst;
    if (i < nx4) {
        src = x; dst = xb;
    } else {
        i -= nx4;
        if (i >= nw4) return;
        src = w; dst = wb;
    }
    float4 v = ((const float4*)src)[i];
    ushort4 o;
    o.x = f2bf(v.x); o.y = f2bf(v.y); o.z = f2bf(v.z); o.w = f2bf(v.w);
    ((ushort4*)dst)[i] = o;
}

// R10: R8's data path (BM=256 x BN=128, BK=64, 8 waves of 64x64, triple-buffer
// LDS 3x48KB A+B, counted vmcnt, 256 blocks = 1/CU) with the sync halved.
// R9 post-mortem: A-from-global = 16-line gathers + register overflow -> dead;
// LDS traffic is geometry-locked at 176 KB/tile (reads 128 + stage-writes 48)
// ~ 1600-1900 cyc vs MFMA 1242; R8's 2850 cyc/tile = floor + ~950 cyc of sync
// (4 wait-points, incl. a mid-phase block-wide barrier between MFMA clusters).
// R10: ONE barrier + ONE vmcnt per tile, NO manual lgkmcnt (compiler's
// dep-tracked lgkm waits are exact and fine-grained -- m97 asm):
//   ph0: issue kk1 frag reads (pr) + stage h0 -> MFMA(kk0)
//   ph1: stage h1 -> MFMA(kk1)
//   end: vmcnt(6) [kt=30: 0] -> s_barrier -> read next tile kk0 frags from pn
// Ledger at guard: newer-than-stage(kt+1) = stage(kt+2) h0(3)+h1(3) = 6.
// Buffer reuse: all pr reads consumed by ph1 MFMA before the barrier, so the
// barrier that frees pr for staging is the same single end barrier. pn frag
// reads pinned below vmcnt+barrier by sched_barrier(0) fences.
__global__ __launch_bounds__(512, 2)
void gemm_gn_kernel(const unsigned short* __restrict__ A,  // [4096][2048] bf16
                    const unsigned short* __restrict__ W,  // [2048][2048] bf16
                    const float* __restrict__ bias,
                    const float* __restrict__ gnw,
                    const float* __restrict__ gnb,
                    float* __restrict__ out) {
    // buffer b at smem + b*24576: A tile (16384 shorts) then B tile (8192)
    __shared__ __align__(16) unsigned short smem[3 * 24576];  // 144 KB

    const int bc   = blockIdx.x;      // 0..15 col block (128 cols)
    const int br   = blockIdx.y;      // 0..15 row block (256 rows)
    const int tid  = threadIdx.x;     // 0..511
    const int lane = tid & 63;
    const int wave = tid >> 6;        // 0..7
    const int wr   = wave >> 1;       // 0..3 row quarter (64 rows)
    const int wc   = wave & 1;        // 0..1 col half (64 cols = 1 group)
    const int c16  = lane & 15;
    const int quad = lane >> 4;

    f32x4 acc[4][4];
#pragma unroll
    for (int i = 0; i < 4; i++)
#pragma unroll
        for (int j = 0; j < 4; j++) acc[i][j] = (f32x4){0.f, 0.f, 0.f, 0.f};

    // ---- staging addresses ----
    // issue (granule G = tid): row = n*64 + (tid>>3), phys granule tid&7,
    // global granule (tid&7)^(row&7) -> pre-swizzled global source, linear LDS.
    const int r0 = tid >> 3;                        // 0..63
    const int qo = ((tid & 7) ^ (r0 & 7)) * 8;      // element offset in row
    const unsigned short* gA = A + (size_t)(br * 256 + r0) * C_IN + qo;
    const unsigned short* gB = W + (size_t)(bc * 128 + r0) * C_IN + qo;
    const int t8 = tid * 8;

    // half 0: A rows 0..127 (2 issues) + B rows 0..63 (1 issue) = 3 loads
    // half 1: A rows 128..255 + B rows 64..127 = 3 loads
#define STAGE_H(dst, k0, half)                                                                      \
    do {                                                                                            \
        _Pragma("unroll")                                                                           \
        for (int n = (half) * 2; n < (half) * 2 + 2; n++)                                           \
            __builtin_amdgcn_global_load_lds(                                                       \
                (const __attribute__((address_space(1))) void*)(gA + (size_t)(n * 64) * C_IN + (k0)), \
                (__attribute__((address_space(3))) void*)((dst) + n * 4096 + t8), 16, 0, 0);        \
        __builtin_amdgcn_global_load_lds(                                                           \
            (const __attribute__((address_space(1))) void*)(gB + (size_t)((half) * 64) * C_IN + (k0)), \
            (__attribute__((address_space(3))) void*)((dst) + 16384 + (half) * 4096 + t8), 16, 0, 0); \
    } while (0)

    unsigned short* bf0 = smem;
    unsigned short* bf1 = smem + 24576;
    unsigned short* bf2 = smem + 49152;

    // fragment addressing: logical granule q at phys q ^ (c16&7)
    const int qs0 = (quad ^ (c16 & 7)) * 8;        // kk=0 frags
    const int qs1 = ((4 + quad) ^ (c16 & 7)) * 8;  // kk=1 frags
    int offA[4], offB[4];
#pragma unroll
    for (int i = 0; i < 4; i++) offA[i] = (wr * 64 + i * 16 + c16) * 64;
#pragma unroll
    for (int j = 0; j < 4; j++) offB[j] = 16384 + (wc * 64 + j * 16 + c16) * 64;

    // prologue: tiles 0 and 1 in flight (12 loads), wait tile0's 6 only
    STAGE_H(bf0, 0, 0);  STAGE_H(bf0, 0, 1);
    STAGE_H(bf1, 64, 0); STAGE_H(bf1, 64, 1);
    asm volatile("s_waitcnt vmcnt(6)" ::: "memory");
    __builtin_amdgcn_s_barrier();

    const unsigned short* pr = bf0;   // read:  tile kt
    const unsigned short* pn = bf1;   // ready: tile kt+1
    unsigned short*       ps = bf2;   // stage: tile kt+2

    bf16x8 a0[4], b0[4], a1[4], b1[4];
    // pre-read tile0 kk=0 frags
#pragma unroll
    for (int i = 0; i < 4; i++) a0[i] = *(const bf16x8*)(pr + offA[i] + qs0);
#pragma unroll
    for (int j = 0; j < 4; j++) b0[j] = *(const bf16x8*)(pr + offB[j] + qs0);

#pragma unroll 1
    for (int kt = 0; kt < 32; ++kt) {
        const int k2 = (kt + 2) * 64;

        // ---------- phase 0: issue kk1 frag reads + stage h0; MFMA kk0 ----------
#pragma unroll
        for (int i = 0; i < 4; i++) a1[i] = *(const bf16x8*)(pr + offA[i] + qs1);
#pragma unroll
        for (int j = 0; j < 4; j++) b1[j] = *(const bf16x8*)(pr + offB[j] + qs1);
        if (kt < 30) STAGE_H(ps, k2, 0);
        __builtin_amdgcn_s_setprio(1);
#pragma unroll
        for (int i = 0; i < 4; i++)
#pragma unroll
            for (int j = 0; j < 4; j++)
                acc[i][j] = __builtin_amdgcn_mfma_f32_16x16x32_bf16(a0[i], b0[j], acc[i][j], 0, 0, 0);
        __builtin_amdgcn_s_setprio(0);

        // ---------- phase 1: stage h1; MFMA kk1 ----------
        if (kt < 30) STAGE_H(ps, k2, 1);
        __builtin_amdgcn_s_setprio(1);
#pragma unroll
        for (int i = 0; i < 4; i++)
#pragma unroll
            for (int j = 0; j < 4; j++)
                acc[i][j] = __builtin_amdgcn_mfma_f32_16x16x32_bf16(a1[i], b1[j], acc[i][j], 0, 0, 0);
        __builtin_amdgcn_s_setprio(0);

        // ---------- tile boundary: one vmcnt + one barrier ----------
        if (kt < 31) {
            if (kt < 30) asm volatile("s_waitcnt vmcnt(6)" ::: "memory");  // kt+1 landed
            else         asm volatile("s_waitcnt vmcnt(0)" ::: "memory");  // tile 31 landed
            __builtin_amdgcn_sched_barrier(0);
            __builtin_amdgcn_s_barrier();   // frees pr for staging; pn safe to read
            __builtin_amdgcn_sched_barrier(0);
#pragma unroll
            for (int i = 0; i < 4; i++) a0[i] = *(const bf16x8*)(pn + offA[i] + qs0);
#pragma unroll
            for (int j = 0; j < 4; j++) b0[j] = *(const bf16x8*)(pn + offB[j] + qs0);
        }

        // rotate triple buffer
        const unsigned short* tmp = pr;
        pr = pn;
        pn = ps;
        ps = (unsigned short*)tmp;
    }

    // ---- epilogue: bias + GroupNorm + hardtanh (all 8 waves, no LDS) ----
    // acc[i][j][r]: row = br*256 + wr*64 + i*16 + quad*4 + r,
    //               col = bc*128 + wc*64 + j*16 + c16. Wave's 64 cols = 1 group.
    const int colbase = bc * 128 + wc * 64;
    const int rowbase = br * 256 + wr * 64;
    float bv[4], gw[4], gb[4];
#pragma unroll
    for (int j = 0; j < 4; j++) {
        int col = colbase + j * 16 + c16;
        bv[j] = bias[col];
        gw[j] = gnw[col];
        gb[j] = gnb[col];
    }
#pragma unroll
    for (int i = 0; i < 4; i++) {
#pragma unroll
        for (int r = 0; r < 4; r++) {
            float s = 0.f, ss = 0.f;
#pragma unroll
            for (int j = 0; j < 4; j++) {
                float v = acc[i][j][r] + bv[j];
                acc[i][j][r] = v;
                s += v;
                ss += v * v;
            }
#pragma unroll
            for (int m = 1; m < 16; m <<= 1) {
                s  += __shfl_xor(s, m, 64);
                ss += __shfl_xor(ss, m, 64);
            }
            float mean = s * (1.f / 64.f);
            float var  = ss * (1.f / 64.f) - mean * mean;
            float rstd = rsqrtf(var + EPS);
            int row = rowbase + i * 16 + quad * 4 + r;
            float* orow = out + (size_t)row * C_OUT;
#pragma unroll
            for (int j = 0; j < 4; j++) {
                float v = (acc[i][j][r] - mean) * rstd * gw[j] + gb[j];
                v = fminf(1.f, fmaxf(-1.f, v));
                orow[colbase + j * 16 + c16] = v;
            }
        }
    }
}

extern "C" void kernel_launch(void* const* d_in, const int* in_sizes, int n_in,
                              void* d_out, int out_size, void* d_ws, size_t ws_size,
                              hipStream_t stream) {
    const float* x    = (const float*)d_in[0];   // [4096, 2048]
    const float* w    = (const float*)d_in[1];   // [2048, 2048]
    const float* bias = (const float*)d_in[2];   // [2048]
    const float* gnw  = (const float*)d_in[3];   // [2048]
    const float* gnb  = (const float*)d_in[4];   // [2048]
    float* out = (float*)d_out;

    unsigned short* xb = (unsigned short*)d_ws;                        // 16 MB
    unsigned short* wb = xb + (size_t)B_ROWS * C_IN;                   //  8 MB

    const int nx4 = B_ROWS * C_IN / 4;   // 2097152
    const int nw4 = C_OUT * C_IN / 4;    // 1048576
    cvt_f32_bf16_kernel<<<(nx4 + nw4 + 255) / 256, 256, 0, stream>>>(x, w, xb, wb, nx4, nw4);

    dim3 grid(C_OUT / 128, B_ROWS / 256);  // (16, 16) = 256 blocks = exactly 1/CU
    gemm_gn_kernel<<<grid, 512, 0, stream>>>(xb, wb, bias, gnw, gnb, out);
}